// Round 1
// baseline (555.548 us; speedup 1.0000x reference)
//
#include <hip/hip_runtime.h>
#include <math.h>

// Problem constants (fixed by reference).
#define TOKENS      16384     // 8 * 2048
#define HIDDEN_DIM  2048
#define EXPERTS     64
#define CAPSLOT     1024      // per-expert list capacity; counts ~Binom(16384,1/64)=256±16, 1024 is ~48 sigma
#define EXPERT_CAPACITY 512   // 2 * ceil(16384/64)

// ---------------------------------------------------------------------------
// K1: logits GEMM + per-token softmax/top2 + per-expert list build (fused).
// Block = 256 threads = 16 tokens x 16 expert-groups (4 experts per thread).
// Each wave holds 4 tokens; cross-lane reductions stay within 16-lane groups.
// ---------------------------------------------------------------------------
__global__ __launch_bounds__(256) void k_logits_route(
    const float* __restrict__ x, const float* __restrict__ W,
    float* __restrict__ p1o, float* __restrict__ p2o,
    int* __restrict__ top1o, int* __restrict__ top2o,
    int* __restrict__ count1, int* __restrict__ count2,
    int* __restrict__ list1, int* __restrict__ list2)
{
    const int tid   = threadIdx.x;
    const int eg    = tid & 15;          // expert group: experts 4*eg .. 4*eg+3
    const int tl    = tid >> 4;          // token within block (0..15)
    const int token = blockIdx.x * 16 + tl;

    const float* xrow = x + (size_t)token * HIDDEN_DIM;
    const float* wp   = W + 4 * eg;

    float4 a0 = make_float4(0.f, 0.f, 0.f, 0.f);
    float4 a1 = a0, a2 = a0, a3 = a0;

    #pragma unroll 4
    for (int k = 0; k < HIDDEN_DIM; k += 4) {
        float4 xv = *(const float4*)(xrow + k);
        float4 w0 = *(const float4*)(wp + (size_t)(k + 0) * EXPERTS);
        float4 w1 = *(const float4*)(wp + (size_t)(k + 1) * EXPERTS);
        float4 w2 = *(const float4*)(wp + (size_t)(k + 2) * EXPERTS);
        float4 w3 = *(const float4*)(wp + (size_t)(k + 3) * EXPERTS);
        a0.x = fmaf(xv.x, w0.x, a0.x); a0.y = fmaf(xv.x, w0.y, a0.y);
        a0.z = fmaf(xv.x, w0.z, a0.z); a0.w = fmaf(xv.x, w0.w, a0.w);
        a1.x = fmaf(xv.y, w1.x, a1.x); a1.y = fmaf(xv.y, w1.y, a1.y);
        a1.z = fmaf(xv.y, w1.z, a1.z); a1.w = fmaf(xv.y, w1.w, a1.w);
        a2.x = fmaf(xv.z, w2.x, a2.x); a2.y = fmaf(xv.z, w2.y, a2.y);
        a2.z = fmaf(xv.z, w2.z, a2.z); a2.w = fmaf(xv.z, w2.w, a2.w);
        a3.x = fmaf(xv.w, w3.x, a3.x); a3.y = fmaf(xv.w, w3.y, a3.y);
        a3.z = fmaf(xv.w, w3.z, a3.z); a3.w = fmaf(xv.w, w3.w, a3.w);
    }

    float vv[4];
    vv[0] = (a0.x + a1.x) + (a2.x + a3.x);
    vv[1] = (a0.y + a1.y) + (a2.y + a3.y);
    vv[2] = (a0.z + a1.z) + (a2.z + a3.z);
    vv[3] = (a0.w + a1.w) + (a2.w + a3.w);

    // ---- argmax (top-1), first-index tie-break, over 64 experts ----
    float bv = vv[0]; int be = 4 * eg;
    #pragma unroll
    for (int j = 1; j < 4; ++j) {
        if (vv[j] > bv) { bv = vv[j]; be = 4 * eg + j; }
    }
    #pragma unroll
    for (int m = 8; m >= 1; m >>= 1) {
        float ov = __shfl_xor(bv, m);
        int   oe = __shfl_xor(be, m);
        if (ov > bv || (ov == bv && oe < be)) { bv = ov; be = oe; }
    }
    const float m1 = bv;
    const int   e1 = be;

    // ---- argmax excluding top-1 (top-2) ----
    float bv2 = -INFINITY; int be2 = 1 << 30;
    #pragma unroll
    for (int j = 0; j < 4; ++j) {
        int e = 4 * eg + j;
        float val = (e == e1) ? -INFINITY : vv[j];
        if (val > bv2 || (val == bv2 && e < be2)) { bv2 = val; be2 = e; }
    }
    #pragma unroll
    for (int m = 8; m >= 1; m >>= 1) {
        float ov = __shfl_xor(bv2, m);
        int   oe = __shfl_xor(be2, m);
        if (ov > bv2 || (ov == bv2 && oe < be2)) { bv2 = ov; be2 = oe; }
    }
    const int e2 = be2;

    // ---- softmax denominator (max-subtracted) ----
    float s = expf(vv[0] - m1) + expf(vv[1] - m1) + expf(vv[2] - m1) + expf(vv[3] - m1);
    #pragma unroll
    for (int m = 8; m >= 1; m >>= 1) s += __shfl_xor(s, m);

    const float P1 = 1.0f / s;            // exp(m1 - m1) / s
    const float P2 = expf(bv2 - m1) / s;

    if (eg == 0) {
        p1o[token]   = P1;
        p2o[token]   = P2;
        top1o[token] = e1;
        top2o[token] = e2;
        int s1 = atomicAdd(&count1[e1], 1);
        if (s1 < CAPSLOT) list1[e1 * CAPSLOT + s1] = token;
        int s2 = atomicAdd(&count2[e2], 1);
        if (s2 < CAPSLOT) list2[e2 * CAPSLOT + s2] = token;
    }
}

// ---------------------------------------------------------------------------
// K2: per-expert batch-prioritized ranking -> keep flags.
// rank(t) among its expert's assignees = #{t' : p1[t'] > p1[t]
//                                         or (p1[t'] == p1[t] and t' < t)}
// keep1: rank1 < 512.  keep2: rank2 + (pre-drop top1 count) < 512.
// ---------------------------------------------------------------------------
__global__ __launch_bounds__(256) void k_rank(
    const float* __restrict__ p1,
    const int* __restrict__ count1, const int* __restrict__ count2,
    const int* __restrict__ list1, const int* __restrict__ list2,
    int* __restrict__ keep1, int* __restrict__ keep2)
{
    __shared__ float skey[CAPSLOT];
    __shared__ int   stok[CAPSLOT];

    const int e  = blockIdx.x;
    const int n1 = min(count1[e], CAPSLOT);

    for (int i = threadIdx.x; i < n1; i += 256) {
        int t = list1[e * CAPSLOT + i];
        stok[i] = t;
        skey[i] = p1[t];
    }
    __syncthreads();
    for (int i = threadIdx.x; i < n1; i += 256) {
        const float ki = skey[i];
        const int   ti = stok[i];
        int r = 0;
        for (int j = 0; j < n1; ++j) {
            const float kj = skey[j];
            const int   tj = stok[j];
            r += (kj > ki || (kj == ki && tj < ti)) ? 1 : 0;
        }
        keep1[ti] = (r < EXPERT_CAPACITY) ? 1 : 0;
    }
    __syncthreads();

    const int n2 = min(count2[e], CAPSLOT);
    for (int i = threadIdx.x; i < n2; i += 256) {
        int t = list2[e * CAPSLOT + i];
        stok[i] = t;
        skey[i] = p1[t];
    }
    __syncthreads();
    for (int i = threadIdx.x; i < n2; i += 256) {
        const float ki = skey[i];
        const int   ti = stok[i];
        int r = n1;                       // offset: pre-drop top-1 count of this expert
        for (int j = 0; j < n2; ++j) {
            const float kj = skey[j];
            const int   tj = stok[j];
            r += (kj > ki || (kj == ki && tj < ti)) ? 1 : 0;
        }
        keep2[ti] = (r < EXPERT_CAPACITY) ? 1 : 0;
    }
}

// ---------------------------------------------------------------------------
// K3: materialize outputs. d_out = [top_1_mask (16384x64) | router_probs (16384x64)]
// ---------------------------------------------------------------------------
__global__ __launch_bounds__(256) void k_out(
    const float* __restrict__ p1, const float* __restrict__ p2,
    const int* __restrict__ top1, const int* __restrict__ top2,
    const int* __restrict__ keep1, const int* __restrict__ keep2,
    float* __restrict__ out)
{
    const int token = blockIdx.x * 256 + threadIdx.x;
    const int  k1 = keep1[token];
    const int  k2 = keep2[token];
    const float P1 = k1 ? p1[token] : 0.0f;
    const float P2 = k2 ? p2[token] : 0.0f;
    float denom = P1 + P2;
    denom = fmaxf(denom, 1.1920929e-07f);   // float32 eps clip
    const float g1 = P1 / denom;
    const float g2 = P2 / denom;
    const int e1 = top1[token];
    const int e2 = top2[token];

    float* mrow = out + (size_t)token * EXPERTS;
    float* prow = out + (size_t)TOKENS * EXPERTS + (size_t)token * EXPERTS;

    const float4 z = make_float4(0.f, 0.f, 0.f, 0.f);
    #pragma unroll
    for (int i = 0; i < 16; ++i) ((float4*)mrow)[i] = z;
    #pragma unroll
    for (int i = 0; i < 16; ++i) ((float4*)prow)[i] = z;

    if (k1) { mrow[e1] = 1.0f; prow[e1] = g1; }
    if (k2) { prow[e2] = g2; }
}

// ---------------------------------------------------------------------------
extern "C" void kernel_launch(void* const* d_in, const int* in_sizes, int n_in,
                              void* d_out, int out_size, void* d_ws, size_t ws_size,
                              hipStream_t stream)
{
    const float* x = (const float*)d_in[0];   // (8,2048,2048) fp32
    const float* W = (const float*)d_in[1];   // (2048,64) fp32
    float* out = (float*)d_out;               // 2 * 16384 * 64 fp32

    // workspace layout
    char* ws = (char*)d_ws;
    float* p1    = (float*)ws;                 // TOKENS
    float* p2    = p1 + TOKENS;                // TOKENS
    int*   top1  = (int*)(p2 + TOKENS);        // TOKENS
    int*   top2  = top1 + TOKENS;              // TOKENS
    int*   keep1 = top2 + TOKENS;              // TOKENS
    int*   keep2 = keep1 + TOKENS;             // TOKENS
    int*   count1 = keep2 + TOKENS;            // EXPERTS
    int*   count2 = count1 + EXPERTS;          // EXPERTS
    int*   list1  = count2 + EXPERTS;          // EXPERTS * CAPSLOT
    int*   list2  = list1 + EXPERTS * CAPSLOT; // EXPERTS * CAPSLOT
    // total ~= 6*16384*4 + 512 + 2*64*1024*4 = ~0.92 MB

    hipMemsetAsync(count1, 0, 2 * EXPERTS * sizeof(int), stream);

    k_logits_route<<<TOKENS / 16, 256, 0, stream>>>(
        x, W, p1, p2, top1, top2, count1, count2, list1, list2);
    k_rank<<<EXPERTS, 256, 0, stream>>>(
        p1, count1, count2, list1, list2, keep1, keep2);
    k_out<<<TOKENS / 256, 256, 0, stream>>>(
        p1, p2, top1, top2, keep1, keep2, out);
}

// Round 3
// 383.734 us; speedup vs baseline: 1.4477x; 1.4477x over previous
//
#include <hip/hip_runtime.h>
#include <math.h>

// Problem constants (fixed by reference).
#define TOKENS      16384     // 8 * 2048
#define HIDDEN_DIM  2048
#define EXPERTS     64
#define CAPSLOT     1024      // per-expert list cap; counts ~Binom(16384,1/64)=256±16
#define EXPERT_CAPACITY 512   // 2 * ceil(16384/64)

#define KC    128             // k-tile (W tile = KC*64 floats = 32 KB)
#define T_BLK 32              // tokens per block

// async global->LDS, 16 bytes per lane. LDS dest = wave-uniform base + lane*16.
__device__ __forceinline__ void load_lds_128(const float* gptr, float* ldsptr) {
    __builtin_amdgcn_global_load_lds(
        (const __attribute__((address_space(1))) void*)gptr,
        (__attribute__((address_space(3))) void*)ldsptr,
        16, 0, 0);
}

__device__ __forceinline__ void fma4(float* a, float s, float4 wv) {
    a[0] = fmaf(s, wv.x, a[0]);
    a[1] = fmaf(s, wv.y, a[1]);
    a[2] = fmaf(s, wv.z, a[2]);
    a[3] = fmaf(s, wv.w, a[3]);
}

// ---------------------------------------------------------------------------
// K1: LDS-tiled logits GEMM + softmax/top2 + per-expert list build (fused).
// 256 threads = 16 expert-groups x 16 token-lanes; token-lane owns 2 tokens.
// W k-tile double-buffered in LDS (2 x 32 KB), staged with global_load_lds.
// ---------------------------------------------------------------------------
__global__ __launch_bounds__(256) void k_logits_route(
    const float* __restrict__ x, const float* __restrict__ W,
    float* __restrict__ p1o, float* __restrict__ p2o,
    int* __restrict__ top1o, int* __restrict__ top2o,
    int* __restrict__ count1, int* __restrict__ count2,
    int* __restrict__ list1, int* __restrict__ list2)
{
    __shared__ float wlds[2][KC * EXPERTS];   // 2 x 32 KB

    const int tid  = threadIdx.x;
    const int eg   = tid & 15;                // experts 4*eg .. 4*eg+3
    const int tl   = tid >> 4;                // token-lane (0..15)
    const int wave = tid >> 6;                // wave id within block
    const int t0   = blockIdx.x * T_BLK + tl * 2;

    const float* xr0 = x + (size_t)t0 * HIDDEN_DIM;
    const float* xr1 = xr0 + HIDDEN_DIM;

    float acc0[4] = {0.f, 0.f, 0.f, 0.f};
    float acc1[4] = {0.f, 0.f, 0.f, 0.f};

    // stage W tile [kt, kt+KC) into wlds[buf]
    auto stage = [&](int kt, int buf) {
        const float* gbase = W + (size_t)kt * EXPERTS;
        #pragma unroll
        for (int i = 0; i < (KC * EXPERTS) / (256 * 4); ++i) {   // 8 iters
            const int f = i * 256 + tid;                          // float4 idx
            load_lds_128(gbase + (size_t)f * 4,
                         &wlds[buf][(i * 256 + wave * 64) * 4]);
        }
    };

    int cur = 0;
    stage(0, 0);
    __syncthreads();

    for (int kt = 0; kt < HIDDEN_DIM; kt += KC) {
        if (kt + KC < HIDDEN_DIM) stage(kt + KC, cur ^ 1);  // async prefetch

        const float* wb = &wlds[cur][0];
        #pragma unroll 4
        for (int k4 = 0; k4 < KC; k4 += 4) {
            float4 xv0 = *(const float4*)(xr0 + kt + k4);
            float4 xv1 = *(const float4*)(xr1 + kt + k4);
            float4 w0 = *(const float4*)(wb + (k4 + 0) * EXPERTS + 4 * eg);
            float4 w1 = *(const float4*)(wb + (k4 + 1) * EXPERTS + 4 * eg);
            float4 w2 = *(const float4*)(wb + (k4 + 2) * EXPERTS + 4 * eg);
            float4 w3 = *(const float4*)(wb + (k4 + 3) * EXPERTS + 4 * eg);
            fma4(acc0, xv0.x, w0); fma4(acc0, xv0.y, w1);
            fma4(acc0, xv0.z, w2); fma4(acc0, xv0.w, w3);
            fma4(acc1, xv1.x, w0); fma4(acc1, xv1.y, w1);
            fma4(acc1, xv1.z, w2); fma4(acc1, xv1.w, w3);
        }
        __syncthreads();   // ds reads of cur done + prefetch loads drained
        cur ^= 1;
    }

    // ---- per-token routing (softmax/top1/top2), 16-lane groups ----
    #pragma unroll
    for (int tk = 0; tk < 2; ++tk) {
        const float* v = tk ? acc1 : acc0;
        const int token = t0 + tk;

        // top-1 argmax, first-index tie-break
        float bv = v[0]; int be = 4 * eg;
        #pragma unroll
        for (int j = 1; j < 4; ++j)
            if (v[j] > bv) { bv = v[j]; be = 4 * eg + j; }
        #pragma unroll
        for (int m = 8; m >= 1; m >>= 1) {
            float ov = __shfl_xor(bv, m);
            int   oe = __shfl_xor(be, m);
            if (ov > bv || (ov == bv && oe < be)) { bv = ov; be = oe; }
        }
        const float m1 = bv;
        const int   e1 = be;

        // top-2: argmax excluding e1
        float bv2 = -INFINITY; int be2 = 1 << 30;
        #pragma unroll
        for (int j = 0; j < 4; ++j) {
            int e = 4 * eg + j;
            float val = (e == e1) ? -INFINITY : v[j];
            if (val > bv2 || (val == bv2 && e < be2)) { bv2 = val; be2 = e; }
        }
        #pragma unroll
        for (int m = 8; m >= 1; m >>= 1) {
            float ov = __shfl_xor(bv2, m);
            int   oe = __shfl_xor(be2, m);
            if (ov > bv2 || (ov == bv2 && oe < be2)) { bv2 = ov; be2 = oe; }
        }
        const int e2 = be2;

        // softmax denominator
        float s = expf(v[0] - m1) + expf(v[1] - m1)
                + expf(v[2] - m1) + expf(v[3] - m1);
        #pragma unroll
        for (int m = 8; m >= 1; m >>= 1) s += __shfl_xor(s, m);

        if (eg == 0) {
            const float P1 = 1.0f / s;
            const float P2 = expf(bv2 - m1) / s;
            p1o[token]   = P1;
            p2o[token]   = P2;
            top1o[token] = e1;
            top2o[token] = e2;
            int s1 = atomicAdd(&count1[e1], 1);
            if (s1 < CAPSLOT) list1[e1 * CAPSLOT + s1] = token;
            int s2 = atomicAdd(&count2[e2], 1);
            if (s2 < CAPSLOT) list2[e2 * CAPSLOT + s2] = token;
        }
    }
}

// ---------------------------------------------------------------------------
// K2: per-expert batch-prioritized ranking -> keep flags.
// rank(t) = #{t' in same list : p1[t'] > p1[t] or (== and t' < t)}
// keep1: rank1 < 512.  keep2: rank2 + (pre-drop top1 count) < 512.
// ---------------------------------------------------------------------------
__global__ __launch_bounds__(256) void k_rank(
    const float* __restrict__ p1,
    const int* __restrict__ count1, const int* __restrict__ count2,
    const int* __restrict__ list1, const int* __restrict__ list2,
    int* __restrict__ keep1, int* __restrict__ keep2)
{
    __shared__ float skey[CAPSLOT];
    __shared__ int   stok[CAPSLOT];

    const int e  = blockIdx.x;
    const int n1 = min(count1[e], CAPSLOT);

    for (int i = threadIdx.x; i < n1; i += 256) {
        int t = list1[e * CAPSLOT + i];
        stok[i] = t;
        skey[i] = p1[t];
    }
    __syncthreads();
    for (int i = threadIdx.x; i < n1; i += 256) {
        const float ki = skey[i];
        const int   ti = stok[i];
        int r = 0;
        for (int j = 0; j < n1; ++j)
            r += (skey[j] > ki || (skey[j] == ki && stok[j] < ti)) ? 1 : 0;
        keep1[ti] = (r < EXPERT_CAPACITY) ? 1 : 0;
    }
    __syncthreads();

    const int n2 = min(count2[e], CAPSLOT);
    for (int i = threadIdx.x; i < n2; i += 256) {
        int t = list2[e * CAPSLOT + i];
        stok[i] = t;
        skey[i] = p1[t];
    }
    __syncthreads();
    for (int i = threadIdx.x; i < n2; i += 256) {
        const float ki = skey[i];
        const int   ti = stok[i];
        int r = n1;                        // offset by pre-drop top-1 count
        for (int j = 0; j < n2; ++j)
            r += (skey[j] > ki || (skey[j] == ki && stok[j] < ti)) ? 1 : 0;
        keep2[ti] = (r < EXPERT_CAPACITY) ? 1 : 0;
    }
}

// ---------------------------------------------------------------------------
// K3: materialize [top_1_mask | gates], coalesced.
// 16 threads per token row; each thread owns 4 experts (one float4 per row).
// ---------------------------------------------------------------------------
__global__ __launch_bounds__(256) void k_out(
    const float* __restrict__ p1, const float* __restrict__ p2,
    const int* __restrict__ top1, const int* __restrict__ top2,
    const int* __restrict__ keep1, const int* __restrict__ keep2,
    float* __restrict__ out)
{
    const int tid   = threadIdx.x;
    const int token = blockIdx.x * 16 + (tid >> 4);
    const int part  = tid & 15;
    const int eb    = part * 4;

    const int  k1 = keep1[token];
    const int  k2 = keep2[token];
    const float P1 = k1 ? p1[token] : 0.0f;
    const float P2 = k2 ? p2[token] : 0.0f;
    float denom = fmaxf(P1 + P2, 1.1920929e-07f);   // float32 eps clip
    const float g1 = P1 / denom;
    const float g2 = P2 / denom;
    const int e1 = top1[token];
    const int e2 = top2[token];

    float4 mv, pv;
    mv.x = (k1 && e1 == eb + 0) ? 1.0f : 0.0f;
    mv.y = (k1 && e1 == eb + 1) ? 1.0f : 0.0f;
    mv.z = (k1 && e1 == eb + 2) ? 1.0f : 0.0f;
    mv.w = (k1 && e1 == eb + 3) ? 1.0f : 0.0f;
    pv.x = (k1 && e1 == eb + 0) ? g1 : ((k2 && e2 == eb + 0) ? g2 : 0.0f);
    pv.y = (k1 && e1 == eb + 1) ? g1 : ((k2 && e2 == eb + 1) ? g2 : 0.0f);
    pv.z = (k1 && e1 == eb + 2) ? g1 : ((k2 && e2 == eb + 2) ? g2 : 0.0f);
    pv.w = (k1 && e1 == eb + 3) ? g1 : ((k2 && e2 == eb + 3) ? g2 : 0.0f);

    *(float4*)(out + (size_t)token * EXPERTS + eb) = mv;
    *(float4*)(out + (size_t)TOKENS * EXPERTS + (size_t)token * EXPERTS + eb) = pv;
}

// ---------------------------------------------------------------------------
extern "C" void kernel_launch(void* const* d_in, const int* in_sizes, int n_in,
                              void* d_out, int out_size, void* d_ws, size_t ws_size,
                              hipStream_t stream)
{
    const float* x = (const float*)d_in[0];   // (8,2048,2048) fp32
    const float* W = (const float*)d_in[1];   // (2048,64) fp32
    float* out = (float*)d_out;               // 2 * 16384 * 64 fp32

    // workspace layout
    char* ws = (char*)d_ws;
    float* p1    = (float*)ws;                 // TOKENS
    float* p2    = p1 + TOKENS;                // TOKENS
    int*   top1  = (int*)(p2 + TOKENS);        // TOKENS
    int*   top2  = top1 + TOKENS;              // TOKENS
    int*   keep1 = top2 + TOKENS;              // TOKENS
    int*   keep2 = keep1 + TOKENS;             // TOKENS
    int*   count1 = keep2 + TOKENS;            // EXPERTS
    int*   count2 = count1 + EXPERTS;          // EXPERTS
    int*   list1  = count2 + EXPERTS;          // EXPERTS * CAPSLOT
    int*   list2  = list1 + EXPERTS * CAPSLOT; // EXPERTS * CAPSLOT

    (void)hipMemsetAsync(count1, 0, 2 * EXPERTS * sizeof(int), stream);

    k_logits_route<<<TOKENS / T_BLK, 256, 0, stream>>>(
        x, W, p1, p2, top1, top2, count1, count2, list1, list2);
    k_rank<<<EXPERTS, 256, 0, stream>>>(
        p1, count1, count2, list1, list2, keep1, keep2);
    k_out<<<TOKENS / 16, 256, 0, stream>>>(
        p1, p2, top1, top2, keep1, keep2, out);
}